// Round 3
// baseline (161.861 us; speedup 1.0000x reference)
//
#include <hip/hip_runtime.h>
#include <stdint.h>

#define BB 4
#define NN 4096
#define CC 256
#define DD 32

typedef __bf16 bf16;
typedef bf16 bf16x4 __attribute__((ext_vector_type(4)));
typedef bf16 bf16x8 __attribute__((ext_vector_type(8)));
typedef float f32x4 __attribute__((ext_vector_type(4)));
typedef unsigned int u32x4 __attribute__((ext_vector_type(4)));

// ---------------- prep: cast x -> bf16, build WT[320][256] = [Wq|Wk|Wv]^T ----
__global__ void prep_kernel(const float* __restrict__ x,
                            const float* __restrict__ Wq,
                            const float* __restrict__ Wk,
                            const float* __restrict__ Wv,
                            bf16* __restrict__ xb,
                            bf16* __restrict__ WT)
{
    int gt = blockIdx.x * blockDim.x + threadIdx.x;
    int stride = gridDim.x * blockDim.x;
    const int total4 = BB * NN * CC / 4;
    for (int i = gt; i < total4; i += stride) {
        f32x4 v = ((const f32x4*)x)[i];
        bf16x4 o;
        o[0] = (bf16)v[0]; o[1] = (bf16)v[1]; o[2] = (bf16)v[2]; o[3] = (bf16)v[3];
        ((bf16x4*)xb)[i] = o;
    }
    const int wtot = 320 * 256;
    for (int i = gt; i < wtot; i += stride) {
        int d = i >> 8, c = i & 255;
        float val;
        if (d < DD)          val = Wq[c * DD + d];
        else if (d < 2 * DD) val = Wk[c * DD + (d - DD)];
        else                 val = Wv[c * CC + (d - 2 * DD)];
        WT[i] = (bf16)val;
    }
}

// ---------------- proj: [q|k|v] = x @ [Wq|Wk|Wv] via MFMA -------------------
// Outputs: qb,kb as [B][N][32] bf16; v transposed+swizzled:
//   vt elem offset = ((b*64 + tile)*256 + c)*64 + (n_in_tile ^ ((c&7)<<3))
__global__ __launch_bounds__(256) void proj_kernel(
    const bf16* __restrict__ xb, const bf16* __restrict__ WT,
    bf16* __restrict__ qb, bf16* __restrict__ kb, bf16* __restrict__ vt)
{
    int b = blockIdx.x >> 6, nt = blockIdx.x & 63;
    int n0 = nt << 6;
    int tid = threadIdx.x;
    int wid = tid >> 6, lane = tid & 63;
    int lm = lane & 15, g = lane >> 4;

    f32x4 acc[20];
    f32x4 zero4 = {0.f, 0.f, 0.f, 0.f};
#pragma unroll
    for (int i = 0; i < 20; ++i) acc[i] = zero4;

    const bf16* xrow = xb + ((size_t)(b * NN) + n0 + wid * 16 + lm) * CC;
    for (int kc = 0; kc < 8; ++kc) {
        bf16x8 a = *(const bf16x8*)(xrow + kc * 32 + g * 8);
#pragma unroll
        for (int ct = 0; ct < 20; ++ct) {
            bf16x8 w = *(const bf16x8*)(WT + (ct * 16 + lm) * 256 + kc * 32 + g * 8);
            acc[ct] = __builtin_amdgcn_mfma_f32_16x16x32_bf16(a, w, acc[ct], 0, 0, 0);
        }
    }

#pragma unroll
    for (int ct = 0; ct < 20; ++ct) {
        int col = ct * 16 + lm;
        if (ct < 4) {
#pragma unroll
            for (int r = 0; r < 4; ++r) {
                int n = n0 + wid * 16 + g * 4 + r;
                bf16 hv = (bf16)acc[ct][r];
                if (ct < 2) qb[((size_t)(b * NN) + n) * DD + col] = hv;
                else        kb[((size_t)(b * NN) + n) * DD + (col - DD)] = hv;
            }
        } else {
            int c = col - 64;
            int nbase = (wid * 16 + g * 4) ^ ((c & 7) << 3); // XOR only touches bits>=3
            bf16x4 pk;
            pk[0] = (bf16)acc[ct][0]; pk[1] = (bf16)acc[ct][1];
            pk[2] = (bf16)acc[ct][2]; pk[3] = (bf16)acc[ct][3];
            size_t off = (((size_t)(b * 64 + nt)) * 256 + c) * 64 + nbase;
            *(bf16x4*)(vt + off) = pk;
        }
    }
}

// ---------------- attn: flash, channel-split PV, V in registers -------------
// Block: 64 q-rows x (4096/KS) keys. Wave w: QK for rows 16w..16w+15 (all keys),
// PV for ALL 64 rows but only channels 64w..64w+63 (V quarter in VGPRs from L2).
// P (64x64 bf16) shared via double-buffered LDS; one barrier per iteration.
__global__ __launch_bounds__(256, 3) void attn_kernel(
    const bf16* __restrict__ qb, const bf16* __restrict__ kb,
    const bf16* __restrict__ vt, const float* __restrict__ x,
    const float* __restrict__ gamma, float* __restrict__ pacc,
    float* __restrict__ pml, float* __restrict__ out, int KS)
{
    // 2 x 8KB P buffers + 2 x 512B meta (alphas f32[64] @+0, flags u32[4] @+256)
    __shared__ __align__(16) unsigned char lds[17408];
    int bid = blockIdx.x;
    int b, qt, ks;
    if (KS == 4) {
        // XCD-aware decode: batch b -> XCDs {2b,2b+1} so vt/kb stay L2-resident
        int xcd = bid & 7, slot = bid >> 3;
        b = xcd >> 1;
        int idx = (xcd & 1) * 128 + slot;
        qt = idx >> 2; ks = idx & 3;
    } else {
        ks = bid % KS; int t = bid / KS; b = t >> 6; qt = t & 63;
    }
    int bq = b * 64 + qt;
    int n0 = qt << 6;
    int tid = threadIdx.x;
    int w = tid >> 6, lane = tid & 63;
    int lm = lane & 15, g = lane >> 4;

    // Q A-fragment: wave w owns q-rows 16w..16w+15; row=lm, k=8g..8g+7
    bf16x8 qf = *(const bf16x8*)(qb + ((size_t)(b * NN) + n0 + w * 16 + lm) * DD + g * 8);

    f32x4 acc[4][4]; // [row-tile][chan-tile], rows rt*16+4g+r, chans 64w+16ct+lm
    f32x4 zero4 = {0.f, 0.f, 0.f, 0.f};
#pragma unroll
    for (int i = 0; i < 4; ++i)
#pragma unroll
        for (int j = 0; j < 4; ++j) acc[i][j] = zero4;
    float m4[4] = {-1e30f, -1e30f, -1e30f, -1e30f};
    float l4[4] = {0.f, 0.f, 0.f, 0.f};

    int KT = 64 / KS;
    int kt0 = ks * KT;
    for (int kt = kt0; kt < kt0 + KT; ++kt) {
        int cur = kt & 1;
        // K B-fragments (L2): col=lm=key, k=8g..8g+7 — oldest vmem so QK's
        // wait doesn't drain the V loads below
        const bf16* kbase = kb + ((size_t)(b * NN) + (size_t)kt * 64) * DD;
        bf16x8 kf0 = *(const bf16x8*)(kbase + (lm +  0) * DD + g * 8);
        bf16x8 kf1 = *(const bf16x8*)(kbase + (lm + 16) * DD + g * 8);
        bf16x8 kf2 = *(const bf16x8*)(kbase + (lm + 32) * DD + g * 8);
        bf16x8 kf3 = *(const bf16x8*)(kbase + (lm + 48) * DD + g * 8);
        // V B-fragments straight from global (this wave's channel quarter)
        const bf16* vtile = vt + ((size_t)(b * 64 + kt)) * 16384;
        bf16x8 vb[4][2];
#pragma unroll
        for (int ct = 0; ct < 4; ++ct) {
            int c = 64 * w + 16 * ct + lm;
            const bf16* vrow = vtile + c * 64;
            int sw = (c & 7) << 3;
            vb[ct][0] = *(const bf16x8*)(vrow + ((8 * g) ^ sw));
            vb[ct][1] = *(const bf16x8*)(vrow + ((32 + 8 * g) ^ sw));
        }

        f32x4 sv[4];
        sv[0] = __builtin_amdgcn_mfma_f32_16x16x32_bf16(qf, kf0, zero4, 0, 0, 0);
        sv[1] = __builtin_amdgcn_mfma_f32_16x16x32_bf16(qf, kf1, zero4, 0, 0, 0);
        sv[2] = __builtin_amdgcn_mfma_f32_16x16x32_bf16(qf, kf2, zero4, 0, 0, 0);
        sv[3] = __builtin_amdgcn_mfma_f32_16x16x32_bf16(qf, kf3, zero4, 0, 0, 0);

        // S[row=4g+r][key=16t+lm]; row-reduce: in-lane over t + shfl over lm
        float rmax[4], alpha[4];
        int okall = 1;
#pragma unroll
        for (int r = 0; r < 4; ++r) {
            float mx = fmaxf(fmaxf(sv[0][r], sv[1][r]), fmaxf(sv[2][r], sv[3][r]));
            mx = fmaxf(mx, __shfl_xor(mx, 1));
            mx = fmaxf(mx, __shfl_xor(mx, 2));
            mx = fmaxf(mx, __shfl_xor(mx, 4));
            mx = fmaxf(mx, __shfl_xor(mx, 8));
            rmax[r] = mx;
            okall &= (mx <= m4[r] + 8.0f) ? 1 : 0;
        }
        int wave_ok = __all(okall);  // defer-max: skip m-update for this wave
#pragma unroll
        for (int r = 0; r < 4; ++r) {
            if (!wave_ok) {
                float mn = fmaxf(m4[r], rmax[r]);
                alpha[r] = __expf(m4[r] - mn);
                m4[r] = mn;
            } else {
                alpha[r] = 1.0f;
            }
        }
#pragma unroll
        for (int r = 0; r < 4; ++r) {
            float s = 0.f;
#pragma unroll
            for (int t = 0; t < 4; ++t) {
                float p = __expf(sv[t][r] - m4[r]);
                sv[t][r] = p;
                s += p;
            }
            s += __shfl_xor(s, 1);
            s += __shfl_xor(s, 2);
            s += __shfl_xor(s, 4);
            s += __shfl_xor(s, 8);
            l4[r] = l4[r] * alpha[r] + s;
        }
        // P tile [64q x 64k] bf16 -> shared LDS (swizzled), rows 16w+4g+r
        unsigned char* Pb = lds + cur * 8192;
#pragma unroll
        for (int t = 0; t < 4; ++t) {
#pragma unroll
            for (int r = 0; r < 4; ++r) {
                int row = 16 * w + 4 * g + r;
                int byteo = row * 128 + ((32 * t + 2 * lm) ^ ((row & 7) << 4));
                *(bf16*)(Pb + byteo) = (bf16)sv[t][r];
            }
        }
        float* alph = (float*)(lds + 16384 + cur * 512);
        uint32_t* flg = (uint32_t*)(lds + 16384 + cur * 512 + 256);
        if (lm == 0) {
            f32x4 av;
            av[0] = alpha[0]; av[1] = alpha[1]; av[2] = alpha[2]; av[3] = alpha[3];
            *(f32x4*)(alph + 16 * w + 4 * g) = av;
        }
        if (lane == 0) flg[w] = (uint32_t)wave_ok;
        __syncthreads();  // P+alphas visible; V/K loads drained (had QK+softmax to land)

        u32x4 fl = *(const u32x4*)flg;  // 16B broadcast
        if (!(fl[0] & fl[1] & fl[2] & fl[3])) {
#pragma unroll
            for (int rt = 0; rt < 4; ++rt) {
                f32x4 a = *(const f32x4*)(alph + rt * 16 + 4 * g); // broadcast
#pragma unroll
                for (int ct = 0; ct < 4; ++ct) acc[rt][ct] *= a;
            }
        }
        // PV: A = P rows rt*16+lm (k=keys), B = V quarter in regs
#pragma unroll
        for (int rt = 0; rt < 4; ++rt) {
            int pbase = (rt * 16 + lm) * 128;
            int psw = (lm & 7) << 4;
            bf16x8 pa0 = *(const bf16x8*)(Pb + pbase + ((16 * g) ^ psw));
            bf16x8 pa1 = *(const bf16x8*)(Pb + pbase + ((64 + 16 * g) ^ psw));
#pragma unroll
            for (int ct = 0; ct < 4; ++ct) {
                acc[rt][ct] = __builtin_amdgcn_mfma_f32_16x16x32_bf16(pa0, vb[ct][0], acc[rt][ct], 0, 0, 0);
                acc[rt][ct] = __builtin_amdgcn_mfma_f32_16x16x32_bf16(pa1, vb[ct][1], acc[rt][ct], 0, 0, 0);
            }
        }
    }

    if (KS == 1) {
        // share per-row l across waves, then finalize
        __syncthreads();
        float* lsh = (float*)(lds + 16384);
        if (lm == 0) {
            f32x4 lv;
            lv[0] = l4[0]; lv[1] = l4[1]; lv[2] = l4[2]; lv[3] = l4[3];
            *(f32x4*)(lsh + 16 * w + 4 * g) = lv;
        }
        __syncthreads();
        float gam = gamma[0];
#pragma unroll
        for (int rt = 0; rt < 4; ++rt) {
            f32x4 lv = *(const f32x4*)(lsh + rt * 16 + 4 * g);
            f32x4 inv;
            inv[0] = 1.f / lv[0]; inv[1] = 1.f / lv[1];
            inv[2] = 1.f / lv[2]; inv[3] = 1.f / lv[3];
#pragma unroll
            for (int ct = 0; ct < 4; ++ct) {
                int col = 64 * w + 16 * ct + lm;
#pragma unroll
                for (int r = 0; r < 4; ++r) {
                    int n = n0 + rt * 16 + 4 * g + r;
                    size_t idx = ((size_t)(b * NN) + n) * CC + col;
                    out[idx] = x[idx] + gam * acc[rt][ct][r] * inv[r];
                }
            }
        }
    } else {
        float* pa = pacc + ((size_t)(bq * KS + ks)) * (64 * 256);
#pragma unroll
        for (int rt = 0; rt < 4; ++rt) {
#pragma unroll
            for (int ct = 0; ct < 4; ++ct) {
                int col = 64 * w + 16 * ct + lm;
#pragma unroll
                for (int r = 0; r < 4; ++r) {
                    int rowin = rt * 16 + 4 * g + r;
                    pa[rowin * 256 + col] = acc[rt][ct][r];
                }
            }
        }
        if (lm == 0) {
#pragma unroll
            for (int r = 0; r < 4; ++r) {
                int rowin = 16 * w + 4 * g + r;
                size_t mo = ((size_t)(bq * KS + ks) * 64 + rowin) * 2;
                pml[mo + 0] = m4[r];
                pml[mo + 1] = l4[r];
            }
        }
    }
}

// ---------------- combine: merge KS partials + residual epilogue ------------
__global__ __launch_bounds__(256) void combine_kernel(
    const float* __restrict__ pacc, const float* __restrict__ pml,
    const float* __restrict__ x, const float* __restrict__ gamma,
    float* __restrict__ out, int KS)
{
    int tid = threadIdx.x;
    int row = blockIdx.x * 4 + (tid >> 6);   // global row in [0, B*N)
    int lane = tid & 63;
    int bq = row >> 6;
    int r64 = row & 63;

    float m[4], l[4];
    float M = -3e38f;
    for (int ks = 0; ks < KS; ++ks) {
        size_t mo = ((size_t)(bq * KS + ks) * 64 + r64) * 2;
        m[ks] = pml[mo + 0];
        l[ks] = pml[mo + 1];
        M = fmaxf(M, m[ks]);
    }
    float L = 0.f;
    float w[4];
    for (int ks = 0; ks < KS; ++ks) {
        w[ks] = __expf(m[ks] - M);
        L += w[ks] * l[ks];
    }
    float s = gamma[0] / L;

    f32x4 a = {0.f, 0.f, 0.f, 0.f};
    for (int ks = 0; ks < KS; ++ks) {
        const f32x4* pa = (const f32x4*)(pacc + ((size_t)(bq * KS + ks) * 64 + r64) * 256);
        f32x4 v = pa[lane];
        a[0] += w[ks] * v[0]; a[1] += w[ks] * v[1];
        a[2] += w[ks] * v[2]; a[3] += w[ks] * v[3];
    }
    const f32x4* xv = (const f32x4*)(x + (size_t)row * 256);
    f32x4 xi = xv[lane];
    f32x4 o;
    o[0] = xi[0] + s * a[0]; o[1] = xi[1] + s * a[1];
    o[2] = xi[2] + s * a[2]; o[3] = xi[3] + s * a[3];
    ((f32x4*)(out + (size_t)row * 256))[lane] = o;
}

extern "C" void kernel_launch(void* const* d_in, const int* in_sizes, int n_in,
                              void* d_out, int out_size, void* d_ws, size_t ws_size,
                              hipStream_t stream)
{
    const float* x     = (const float*)d_in[0];
    const float* Wq    = (const float*)d_in[1];
    const float* Wk    = (const float*)d_in[2];
    const float* Wv    = (const float*)d_in[3];
    const float* gamma = (const float*)d_in[4];
    float* out = (float*)d_out;

    char* ws = (char*)d_ws;
    bf16* xb = (bf16*)(ws);                  // 8,388,608 B
    bf16* WT = (bf16*)(ws + 8388608);        //   163,840 B
    bf16* qb = (bf16*)(ws + 8552448);        // 1,048,576 B
    bf16* kb = (bf16*)(ws + 9601024);        // 1,048,576 B
    bf16* vt = (bf16*)(ws + 10649600);       // 8,388,608 B  (end 19,038,208)

    const size_t base = 19038208;
    size_t need4 = base + (size_t)4 * (16777216 + 131072);
    size_t need2 = base + (size_t)2 * (16777216 + 131072);
    int KS = (ws_size >= need4) ? 4 : ((ws_size >= need2) ? 2 : 1);

    float* pacc = (float*)(ws + base);
    float* pml  = (float*)(ws + base + (size_t)KS * 16777216);

    hipLaunchKernelGGL(prep_kernel, dim3(1024), dim3(256), 0, stream,
                       x, Wq, Wk, Wv, xb, WT);
    hipLaunchKernelGGL(proj_kernel, dim3(256), dim3(256), 0, stream,
                       xb, WT, qb, kb, vt);
    hipLaunchKernelGGL(attn_kernel, dim3(256 * KS), dim3(256), 0, stream,
                       qb, kb, vt, x, gamma, pacc, pml, out, KS);
    if (KS > 1) {
        hipLaunchKernelGGL(combine_kernel, dim3(BB * NN / 4), dim3(256), 0, stream,
                           pacc, pml, x, gamma, out, KS);
    }
}

// Round 4
// 110.485 us; speedup vs baseline: 1.4650x; 1.4650x over previous
//
#include <hip/hip_runtime.h>
#include <stdint.h>

#define BB 4
#define NN 4096
#define CC 256
#define DD 32

typedef __bf16 bf16;
typedef bf16 bf16x4 __attribute__((ext_vector_type(4)));
typedef bf16 bf16x8 __attribute__((ext_vector_type(8)));
typedef float f32x4 __attribute__((ext_vector_type(4)));
typedef unsigned int u32x4 __attribute__((ext_vector_type(4)));

// ---------------- prep: cast x -> bf16, build WT[320][256] = [Wq|Wk|Wv]^T ----
__global__ void prep_kernel(const float* __restrict__ x,
                            const float* __restrict__ Wq,
                            const float* __restrict__ Wk,
                            const float* __restrict__ Wv,
                            bf16* __restrict__ xb,
                            bf16* __restrict__ WT)
{
    int gt = blockIdx.x * blockDim.x + threadIdx.x;
    int stride = gridDim.x * blockDim.x;
    const int total4 = BB * NN * CC / 4;
    for (int i = gt; i < total4; i += stride) {
        f32x4 v = ((const f32x4*)x)[i];
        bf16x4 o;
        o[0] = (bf16)v[0]; o[1] = (bf16)v[1]; o[2] = (bf16)v[2]; o[3] = (bf16)v[3];
        ((bf16x4*)xb)[i] = o;
    }
    const int wtot = 320 * 256;
    for (int i = gt; i < wtot; i += stride) {
        int d = i >> 8, c = i & 255;
        float val;
        if (d < DD)          val = Wq[c * DD + d];
        else if (d < 2 * DD) val = Wk[c * DD + (d - DD)];
        else                 val = Wv[c * CC + (d - 2 * DD)];
        WT[i] = (bf16)val;
    }
}

// ---------------- proj: [q|k|v] = x @ [Wq|Wk|Wv] via MFMA -------------------
// Outputs: qb,kb as [B][N][32] bf16; v transposed+swizzled:
//   vt elem offset = ((b*64 + tile)*256 + c)*64 + (n_in_tile ^ ((c&7)<<3))
__global__ __launch_bounds__(256) void proj_kernel(
    const bf16* __restrict__ xb, const bf16* __restrict__ WT,
    bf16* __restrict__ qb, bf16* __restrict__ kb, bf16* __restrict__ vt)
{
    int b = blockIdx.x >> 6, nt = blockIdx.x & 63;
    int n0 = nt << 6;
    int tid = threadIdx.x;
    int wid = tid >> 6, lane = tid & 63;
    int lm = lane & 15, g = lane >> 4;

    f32x4 acc[20];
    f32x4 zero4 = {0.f, 0.f, 0.f, 0.f};
#pragma unroll
    for (int i = 0; i < 20; ++i) acc[i] = zero4;

    const bf16* xrow = xb + ((size_t)(b * NN) + n0 + wid * 16 + lm) * CC;
    for (int kc = 0; kc < 8; ++kc) {
        bf16x8 a = *(const bf16x8*)(xrow + kc * 32 + g * 8);
#pragma unroll
        for (int ct = 0; ct < 20; ++ct) {
            bf16x8 w = *(const bf16x8*)(WT + (ct * 16 + lm) * 256 + kc * 32 + g * 8);
            acc[ct] = __builtin_amdgcn_mfma_f32_16x16x32_bf16(a, w, acc[ct], 0, 0, 0);
        }
    }

#pragma unroll
    for (int ct = 0; ct < 20; ++ct) {
        int col = ct * 16 + lm;
        if (ct < 4) {
#pragma unroll
            for (int r = 0; r < 4; ++r) {
                int n = n0 + wid * 16 + g * 4 + r;
                bf16 hv = (bf16)acc[ct][r];
                if (ct < 2) qb[((size_t)(b * NN) + n) * DD + col] = hv;
                else        kb[((size_t)(b * NN) + n) * DD + (col - DD)] = hv;
            }
        } else {
            int c = col - 64;
            int nbase = (wid * 16 + g * 4) ^ ((c & 7) << 3); // XOR only touches bits>=3
            bf16x4 pk;
            pk[0] = (bf16)acc[ct][0]; pk[1] = (bf16)acc[ct][1];
            pk[2] = (bf16)acc[ct][2]; pk[3] = (bf16)acc[ct][3];
            size_t off = (((size_t)(b * 64 + nt)) * 256 + c) * 64 + nbase;
            *(bf16x4*)(vt + off) = pk;
        }
    }
}

// ============ attn v4: swapped QK^T, in-reg softmax, K/V prefetch ============
// Block: 64 q-rows x (4096/KS) keys, 4 waves. Wave w: QK^T (swapped: mfma(K,Q))
// for q-rows 16w..16w+15 -> lane (lm,g) holds S[qrow=16w+lm][key=16t+4g+r].
// Softmax per row is in-lane + 2 shfls. P shared via dbuf LDS; PV channel-split
// (wave w -> chans 64w..64w+63, V quarter in regs). K/V double-buffered regs,
// prefetched one iter ahead; raw s_barrier (no vmcnt drain) keeps them in flight.

#define LOADK(KT_, KF) { \
    const bf16* kbase_ = kb + ((size_t)(b * NN) + (size_t)(KT_) * 64) * DD + g * 8; \
    KF[0] = *(const bf16x8*)(kbase_ + (lm +  0) * DD); \
    KF[1] = *(const bf16x8*)(kbase_ + (lm + 16) * DD); \
    KF[2] = *(const bf16x8*)(kbase_ + (lm + 32) * DD); \
    KF[3] = *(const bf16x8*)(kbase_ + (lm + 48) * DD); }

#define LOADV(KT_, VB) { \
    const bf16* vtile_ = vt + ((size_t)(b * 64 + (KT_))) * 16384; \
    _Pragma("unroll") \
    for (int ct_ = 0; ct_ < 4; ++ct_) { \
        int c_ = 64 * w + 16 * ct_ + lm; \
        const bf16* vrow_ = vtile_ + c_ * 64; \
        int vsw_ = (c_ & 7) << 3; \
        VB[ct_][0] = *(const bf16x8*)(vrow_ + ((8 * g) ^ vsw_)); \
        VB[ct_][1] = *(const bf16x8*)(vrow_ + ((32 + 8 * g) ^ vsw_)); \
    } }

#define STEP(KT_, KF, VB, KFN, VBN) { \
    const int cur_ = (KT_) & 1; \
    f32x4 sv0 = __builtin_amdgcn_mfma_f32_16x16x32_bf16(KF[0], qf, zero4, 0, 0, 0); \
    f32x4 sv1 = __builtin_amdgcn_mfma_f32_16x16x32_bf16(KF[1], qf, zero4, 0, 0, 0); \
    f32x4 sv2 = __builtin_amdgcn_mfma_f32_16x16x32_bf16(KF[2], qf, zero4, 0, 0, 0); \
    f32x4 sv3 = __builtin_amdgcn_mfma_f32_16x16x32_bf16(KF[3], qf, zero4, 0, 0, 0); \
    int ktn_ = ((KT_) + 1 < kt1) ? ((KT_) + 1) : (kt1 - 1); \
    LOADK(ktn_, KFN); \
    LOADV(ktn_, VBN); \
    float mx_ = fmaxf(fmaxf(fmaxf(sv0[0], sv0[1]), fmaxf(sv0[2], sv0[3])), \
                      fmaxf(fmaxf(sv1[0], sv1[1]), fmaxf(sv1[2], sv1[3]))); \
    mx_ = fmaxf(mx_, fmaxf(fmaxf(sv2[0], sv2[1]), fmaxf(sv2[2], sv2[3]))); \
    mx_ = fmaxf(mx_, fmaxf(fmaxf(sv3[0], sv3[1]), fmaxf(sv3[2], sv3[3]))); \
    mx_ = fmaxf(mx_, __shfl_xor(mx_, 16)); \
    mx_ = fmaxf(mx_, __shfl_xor(mx_, 32)); \
    float alpha_; \
    int wave_ok_ = __all(mx_ <= mrun + 8.0f); \
    if (!wave_ok_) { float mn_ = fmaxf(mrun, mx_); alpha_ = __expf(mrun - mn_); mrun = mn_; } \
    else alpha_ = 1.0f; \
    float ssum_; \
    { \
        _Pragma("unroll") for (int j_ = 0; j_ < 4; ++j_) sv0[j_] = __expf(sv0[j_] - mrun); \
        _Pragma("unroll") for (int j_ = 0; j_ < 4; ++j_) sv1[j_] = __expf(sv1[j_] - mrun); \
        _Pragma("unroll") for (int j_ = 0; j_ < 4; ++j_) sv2[j_] = __expf(sv2[j_] - mrun); \
        _Pragma("unroll") for (int j_ = 0; j_ < 4; ++j_) sv3[j_] = __expf(sv3[j_] - mrun); \
        f32x4 t_ = (sv0 + sv1) + (sv2 + sv3); \
        ssum_ = (t_[0] + t_[1]) + (t_[2] + t_[3]); \
        ssum_ += __shfl_xor(ssum_, 16); \
        ssum_ += __shfl_xor(ssum_, 32); \
    } \
    lrun = lrun * alpha_ + ssum_; \
    unsigned char* Pb_ = lds + cur_ * 8192; \
    { \
        int rb_ = (16 * w + lm) * 128; \
        int sw_ = (lm & 7) << 4; \
        bf16x4 pk_; \
        pk_[0] = (bf16)sv0[0]; pk_[1] = (bf16)sv0[1]; pk_[2] = (bf16)sv0[2]; pk_[3] = (bf16)sv0[3]; \
        *(bf16x4*)(Pb_ + rb_ + (( 0 + 8 * g) ^ sw_)) = pk_; \
        pk_[0] = (bf16)sv1[0]; pk_[1] = (bf16)sv1[1]; pk_[2] = (bf16)sv1[2]; pk_[3] = (bf16)sv1[3]; \
        *(bf16x4*)(Pb_ + rb_ + ((32 + 8 * g) ^ sw_)) = pk_; \
        pk_[0] = (bf16)sv2[0]; pk_[1] = (bf16)sv2[1]; pk_[2] = (bf16)sv2[2]; pk_[3] = (bf16)sv2[3]; \
        *(bf16x4*)(Pb_ + rb_ + ((64 + 8 * g) ^ sw_)) = pk_; \
        pk_[0] = (bf16)sv3[0]; pk_[1] = (bf16)sv3[1]; pk_[2] = (bf16)sv3[2]; pk_[3] = (bf16)sv3[3]; \
        *(bf16x4*)(Pb_ + rb_ + ((96 + 8 * g) ^ sw_)) = pk_; \
    } \
    float* alph_ = (float*)(lds + 16384 + cur_ * 512); \
    uint32_t* flg_ = (uint32_t*)(lds + 16384 + cur_ * 512 + 256); \
    if (g == 0) alph_[16 * w + lm] = alpha_; \
    if (lane == 0) flg_[w] = (uint32_t)wave_ok_; \
    asm volatile("s_waitcnt lgkmcnt(0)" ::: "memory"); \
    __builtin_amdgcn_s_barrier(); \
    asm volatile("" ::: "memory"); \
    { \
        u32x4 fl_ = *(const u32x4*)flg_; \
        if ((fl_[0] & fl_[1] & fl_[2] & fl_[3]) == 0u) { \
            _Pragma("unroll") for (int rt_ = 0; rt_ < 4; ++rt_) { \
                f32x4 a_ = *(const f32x4*)(alph_ + rt_ * 16 + 4 * g); \
                _Pragma("unroll") for (int ct_ = 0; ct_ < 4; ++ct_) { \
                    acc[rt_][ct_][0] *= a_[0]; acc[rt_][ct_][1] *= a_[1]; \
                    acc[rt_][ct_][2] *= a_[2]; acc[rt_][ct_][3] *= a_[3]; \
                } \
            } \
        } \
    } \
    __builtin_amdgcn_s_setprio(1); \
    { \
        int psw_ = (lm & 7) << 4; \
        _Pragma("unroll") for (int rt_ = 0; rt_ < 4; ++rt_) { \
            const unsigned char* pr_ = Pb_ + (rt_ * 16 + lm) * 128; \
            bf16x8 pa0_ = *(const bf16x8*)(pr_ + (( 0 + 16 * g) ^ psw_)); \
            bf16x8 pa1_ = *(const bf16x8*)(pr_ + ((64 + 16 * g) ^ psw_)); \
            _Pragma("unroll") for (int ct_ = 0; ct_ < 4; ++ct_) { \
                acc[rt_][ct_] = __builtin_amdgcn_mfma_f32_16x16x32_bf16(pa0_, VB[ct_][0], acc[rt_][ct_], 0, 0, 0); \
                acc[rt_][ct_] = __builtin_amdgcn_mfma_f32_16x16x32_bf16(pa1_, VB[ct_][1], acc[rt_][ct_], 0, 0, 0); \
            } \
        } \
    } \
    __builtin_amdgcn_s_setprio(0); \
}

__global__ __launch_bounds__(256, 2) void attn_kernel(
    const bf16* __restrict__ qb, const bf16* __restrict__ kb,
    const bf16* __restrict__ vt, const float* __restrict__ x,
    const float* __restrict__ gamma, float* __restrict__ pacc,
    float* __restrict__ pml, float* __restrict__ out, int KS)
{
    // 2 x 8KB P buffers + 2 x 512B meta (alphas f32[64] @+0, flags u32[4] @+256)
    __shared__ __align__(16) unsigned char lds[17408];
    int bid = blockIdx.x;
    int b, qt, ks;
    if (KS == 4) {
        // XCD-aware decode: batch b -> XCDs {2b,2b+1} so vt/kb stay L2-resident
        int xcd = bid & 7, slot = bid >> 3;
        b = xcd >> 1;
        int idx = (xcd & 1) * 128 + slot;
        qt = idx >> 2; ks = idx & 3;
    } else {
        ks = bid % KS; int t = bid / KS; b = t >> 6; qt = t & 63;
    }
    int bq = b * 64 + qt;
    int n0 = qt << 6;
    int tid = threadIdx.x;
    int w = tid >> 6, lane = tid & 63;
    int lm = lane & 15, g = lane >> 4;

    // Q fragment (used as MFMA B-operand: col=qrow=lm, k=8g..8g+7)
    bf16x8 qf = *(const bf16x8*)(qb + ((size_t)(b * NN) + n0 + w * 16 + lm) * DD + g * 8);

    f32x4 acc[4][4]; // [row-tile][chan-tile], rows rt*16+4g+r, chans 64w+16ct+lm
    f32x4 zero4 = {0.f, 0.f, 0.f, 0.f};
#pragma unroll
    for (int i = 0; i < 4; ++i)
#pragma unroll
        for (int j = 0; j < 4; ++j) acc[i][j] = zero4;
    float mrun = -1e30f, lrun = 0.f;

    int KT = 64 / KS;
    int kt0 = ks * KT;
    int kt1 = kt0 + KT;

    bf16x8 kfA[4], kfB[4];
    bf16x8 vbA[4][2], vbB[4][2];
    LOADK(kt0, kfA);
    LOADV(kt0, vbA);

    for (int kt = kt0; kt < kt1; kt += 2) {
        STEP(kt,     kfA, vbA, kfB, vbB);
        STEP(kt + 1, kfB, vbB, kfA, vbA);
    }

    if (KS == 1) {
        __syncthreads();
        float* lsh = (float*)(lds + 16384);
        if (g == 0) lsh[16 * w + lm] = lrun;
        __syncthreads();
        float gam = gamma[0];
#pragma unroll
        for (int rt = 0; rt < 4; ++rt) {
            f32x4 lv = *(const f32x4*)(lsh + rt * 16 + 4 * g);
            f32x4 inv;
            inv[0] = 1.f / lv[0]; inv[1] = 1.f / lv[1];
            inv[2] = 1.f / lv[2]; inv[3] = 1.f / lv[3];
#pragma unroll
            for (int ct = 0; ct < 4; ++ct) {
                int col = 64 * w + 16 * ct + lm;
#pragma unroll
                for (int r = 0; r < 4; ++r) {
                    int n = n0 + rt * 16 + 4 * g + r;
                    size_t idx = ((size_t)(b * NN) + n) * CC + col;
                    out[idx] = x[idx] + gam * acc[rt][ct][r] * inv[r];
                }
            }
        }
    } else {
        float* pa = pacc + ((size_t)(bq * KS + ks)) * (64 * 256);
#pragma unroll
        for (int rt = 0; rt < 4; ++rt) {
#pragma unroll
            for (int ct = 0; ct < 4; ++ct) {
                int col = 64 * w + 16 * ct + lm;
#pragma unroll
                for (int r = 0; r < 4; ++r) {
                    int rowin = rt * 16 + 4 * g + r;
                    pa[rowin * 256 + col] = acc[rt][ct][r];
                }
            }
        }
        if (g == 0) {
            int rowin = 16 * w + lm;
            size_t mo = ((size_t)(bq * KS + ks) * 64 + rowin) * 2;
            pml[mo + 0] = mrun;
            pml[mo + 1] = lrun;
        }
    }
}

// ---------------- combine: merge KS partials + residual epilogue ------------
__global__ __launch_bounds__(256) void combine_kernel(
    const float* __restrict__ pacc, const float* __restrict__ pml,
    const float* __restrict__ x, const float* __restrict__ gamma,
    float* __restrict__ out, int KS)
{
    int tid = threadIdx.x;
    int row = blockIdx.x * 4 + (tid >> 6);   // global row in [0, B*N)
    int lane = tid & 63;
    int bq = row >> 6;
    int r64 = row & 63;

    float m[4], l[4];
    float M = -3e38f;
    for (int ks = 0; ks < KS; ++ks) {
        size_t mo = ((size_t)(bq * KS + ks) * 64 + r64) * 2;
        m[ks] = pml[mo + 0];
        l[ks] = pml[mo + 1];
        M = fmaxf(M, m[ks]);
    }
    float L = 0.f;
    float w[4];
    for (int ks = 0; ks < KS; ++ks) {
        w[ks] = __expf(m[ks] - M);
        L += w[ks] * l[ks];
    }
    float s = gamma[0] / L;

    f32x4 a = {0.f, 0.f, 0.f, 0.f};
    for (int ks = 0; ks < KS; ++ks) {
        const f32x4* pa = (const f32x4*)(pacc + ((size_t)(bq * KS + ks) * 64 + r64) * 256);
        f32x4 v = pa[lane];
        a[0] += w[ks] * v[0]; a[1] += w[ks] * v[1];
        a[2] += w[ks] * v[2]; a[3] += w[ks] * v[3];
    }
    const f32x4* xv = (const f32x4*)(x + (size_t)row * 256);
    f32x4 xi = xv[lane];
    f32x4 o;
    o[0] = xi[0] + s * a[0]; o[1] = xi[1] + s * a[1];
    o[2] = xi[2] + s * a[2]; o[3] = xi[3] + s * a[3];
    ((f32x4*)(out + (size_t)row * 256))[lane] = o;
}

extern "C" void kernel_launch(void* const* d_in, const int* in_sizes, int n_in,
                              void* d_out, int out_size, void* d_ws, size_t ws_size,
                              hipStream_t stream)
{
    const float* x     = (const float*)d_in[0];
    const float* Wq    = (const float*)d_in[1];
    const float* Wk    = (const float*)d_in[2];
    const float* Wv    = (const float*)d_in[3];
    const float* gamma = (const float*)d_in[4];
    float* out = (float*)d_out;

    char* ws = (char*)d_ws;
    bf16* xb = (bf16*)(ws);                  // 8,388,608 B
    bf16* WT = (bf16*)(ws + 8388608);        //   163,840 B
    bf16* qb = (bf16*)(ws + 8552448);        // 1,048,576 B
    bf16* kb = (bf16*)(ws + 9601024);        // 1,048,576 B
    bf16* vt = (bf16*)(ws + 10649600);       // 8,388,608 B  (end 19,038,208)

    const size_t base = 19038208;
    size_t need4 = base + (size_t)4 * (16777216 + 131072);
    size_t need2 = base + (size_t)2 * (16777216 + 131072);
    int KS = (ws_size >= need4) ? 4 : ((ws_size >= need2) ? 2 : 1);

    float* pacc = (float*)(ws + base);
    float* pml  = (float*)(ws + base + (size_t)KS * 16777216);

    hipLaunchKernelGGL(prep_kernel, dim3(1024), dim3(256), 0, stream,
                       x, Wq, Wk, Wv, xb, WT);
    hipLaunchKernelGGL(proj_kernel, dim3(256), dim3(256), 0, stream,
                       xb, WT, qb, kb, vt);
    hipLaunchKernelGGL(attn_kernel, dim3(256 * KS), dim3(256), 0, stream,
                       qb, kb, vt, x, gamma, pacc, pml, out, KS);
    if (KS > 1) {
        hipLaunchKernelGGL(combine_kernel, dim3(BB * NN / 4), dim3(256), 0, stream,
                           pacc, pml, x, gamma, out, KS);
    }
}